// Round 11
// baseline (347.223 us; speedup 1.0000x reference)
//
#include <hip/hip_runtime.h>
#include <math.h>

// Problem constants
#define BB 2
#define LL 2048
#define KK 2048
#define DD 512
#define HH 8
#define HD_ 64
#define RR 8
#define WWIN 8
#define NE (LL * WWIN)   // 16384 edges per batch

typedef __attribute__((ext_vector_type(8))) short bf16x8s;
typedef __attribute__((ext_vector_type(4))) float f32x4;

__device__ __forceinline__ float gelu_f(float x) {
    return 0.5f * x * (1.0f + erff(x * 0.70710678118654752f));
}
__device__ __forceinline__ float softplus_f(float x) {
    return (x > 20.0f) ? x : log1pf(expf(x));
}
__device__ __forceinline__ unsigned short f2bf(float f) {
    unsigned int x = __float_as_uint(f);
    x += 0x7FFFu + ((x >> 16) & 1u);   // RTNE
    return (unsigned short)(x >> 16);
}
__device__ __forceinline__ float bf2f(unsigned short s) {
    return __uint_as_float(((unsigned int)s) << 16);
}

#define GEMM_SMEM_BYTES 15360   // max(bf16: 10240+5120, f32: 4352+4352)

// ---------------------------------------------------------------------------
// bf16-MFMA GEMM body: C[M,N] = A[M,Kd]@W[Kd,N] (+bias), f32 in/out.
// Tile 128x64, BK=32, 4 waves (2M x 2N), wave tile 64x32, frags 4x2 of 16x16.
// ---------------------------------------------------------------------------
__device__ __forceinline__ void gemm_bf16_body(
    const float* __restrict__ A, const float* __restrict__ W,
    const float* __restrict__ bias, float* __restrict__ C,
    int M, int N, int Kd, int bx, int by, char* smem) {
    short (*As)[40] = (short(*)[40])smem;
    short (*Bs)[40] = (short(*)[40])(smem + 128 * 40 * 2);
    const int tid = threadIdx.x;
    const int m0 = bx * 128, n0 = by * 64;
    const int wv = tid >> 6, lane = tid & 63;
    const int wm = (wv & 1) << 6, wn = (wv >> 1) << 5;
    const int l15 = lane & 15, lg = lane >> 4;

    f32x4 acc[4][2] = {};
    union S8 { bf16x8s v; short s[8]; };

    const int arow = tid >> 1, akh = (tid & 1) << 4;
    const int bk = tid >> 3, bnb = (tid & 7) << 3;

    for (int k0 = 0; k0 < Kd; k0 += 32) {
        {
            const float* ap = &A[(size_t)(m0 + arow) * Kd + k0 + akh];
            float4 f0 = *(const float4*)(ap + 0);
            float4 f1 = *(const float4*)(ap + 4);
            float4 f2 = *(const float4*)(ap + 8);
            float4 f3 = *(const float4*)(ap + 12);
            S8 s0, s1;
            s0.s[0] = f2bf(f0.x); s0.s[1] = f2bf(f0.y); s0.s[2] = f2bf(f0.z); s0.s[3] = f2bf(f0.w);
            s0.s[4] = f2bf(f1.x); s0.s[5] = f2bf(f1.y); s0.s[6] = f2bf(f1.z); s0.s[7] = f2bf(f1.w);
            s1.s[0] = f2bf(f2.x); s1.s[1] = f2bf(f2.y); s1.s[2] = f2bf(f2.z); s1.s[3] = f2bf(f2.w);
            s1.s[4] = f2bf(f3.x); s1.s[5] = f2bf(f3.y); s1.s[6] = f2bf(f3.z); s1.s[7] = f2bf(f3.w);
            *(bf16x8s*)&As[arow][akh] = s0.v;
            *(bf16x8s*)&As[arow][akh + 8] = s1.v;
        }
        {
            const float* wp = &W[(size_t)(k0 + bk) * N + n0 + bnb];
            float4 w0 = *(const float4*)(wp + 0);
            float4 w1 = *(const float4*)(wp + 4);
            Bs[bnb + 0][bk] = f2bf(w0.x);
            Bs[bnb + 1][bk] = f2bf(w0.y);
            Bs[bnb + 2][bk] = f2bf(w0.z);
            Bs[bnb + 3][bk] = f2bf(w0.w);
            Bs[bnb + 4][bk] = f2bf(w1.x);
            Bs[bnb + 5][bk] = f2bf(w1.y);
            Bs[bnb + 6][bk] = f2bf(w1.z);
            Bs[bnb + 7][bk] = f2bf(w1.w);
        }
        __syncthreads();
        bf16x8s af[4], bf[2];
#pragma unroll
        for (int mf = 0; mf < 4; ++mf)
            af[mf] = *(const bf16x8s*)&As[wm + (mf << 4) + l15][lg << 3];
#pragma unroll
        for (int nf = 0; nf < 2; ++nf)
            bf[nf] = *(const bf16x8s*)&Bs[wn + (nf << 4) + l15][lg << 3];
#pragma unroll
        for (int mf = 0; mf < 4; ++mf)
#pragma unroll
            for (int nf = 0; nf < 2; ++nf)
                acc[mf][nf] = __builtin_amdgcn_mfma_f32_16x16x32_bf16(af[mf], bf[nf], acc[mf][nf], 0, 0, 0);
        __syncthreads();
    }
    float bv[2] = {0.f, 0.f};
    if (bias) {
        bv[0] = bias[n0 + wn + l15];
        bv[1] = bias[n0 + wn + 16 + l15];
    }
#pragma unroll
    for (int mf = 0; mf < 4; ++mf)
#pragma unroll
        for (int nf = 0; nf < 2; ++nf)
#pragma unroll
            for (int j = 0; j < 4; ++j) {
                int crow = m0 + wm + (mf << 4) + (lg << 2) + j;
                int ccol = n0 + wn + (nf << 4) + l15;
                C[(size_t)crow * N + ccol] = acc[mf][nf][j] + bv[nf];
            }
}

// ---------------------------------------------------------------------------
// f32 GEMM body (kept for t64/c64: exact scores -> stable top-k).
// ---------------------------------------------------------------------------
__device__ __forceinline__ void gemm_f32_body(
    const float* __restrict__ A, const float* __restrict__ W,
    float* __restrict__ C, int M, int N, int Kd, int bx, int by, char* smem) {
    float (*As)[68] = (float(*)[68])smem;
    float (*Bs)[68] = (float(*)[68])(smem + 16 * 68 * 4);
    const int tid = threadIdx.x;
    const int m0 = bx * 64, n0 = by * 64;
    const int tx = tid & 15, ty = tid >> 4;
    const int row_a = tid >> 2, kq_a = (tid & 3) << 2;
    const int kw = tid >> 4, nq = (tid & 15) << 2;
    float acc[4][4] = {};
    for (int k0 = 0; k0 < Kd; k0 += 16) {
        float4 av = *(const float4*)&A[(size_t)(m0 + row_a) * Kd + k0 + kq_a];
        As[kq_a + 0][row_a] = av.x;
        As[kq_a + 1][row_a] = av.y;
        As[kq_a + 2][row_a] = av.z;
        As[kq_a + 3][row_a] = av.w;
        *(float4*)&Bs[kw][nq] = *(const float4*)&W[(size_t)(k0 + kw) * N + n0 + nq];
        __syncthreads();
#pragma unroll
        for (int k = 0; k < 16; ++k) {
            float4 a4 = *(const float4*)&As[k][ty << 2];
            float4 b4 = *(const float4*)&Bs[k][tx << 2];
            acc[0][0] = fmaf(a4.x, b4.x, acc[0][0]);
            acc[0][1] = fmaf(a4.x, b4.y, acc[0][1]);
            acc[0][2] = fmaf(a4.x, b4.z, acc[0][2]);
            acc[0][3] = fmaf(a4.x, b4.w, acc[0][3]);
            acc[1][0] = fmaf(a4.y, b4.x, acc[1][0]);
            acc[1][1] = fmaf(a4.y, b4.y, acc[1][1]);
            acc[1][2] = fmaf(a4.y, b4.z, acc[1][2]);
            acc[1][3] = fmaf(a4.y, b4.w, acc[1][3]);
            acc[2][0] = fmaf(a4.z, b4.x, acc[2][0]);
            acc[2][1] = fmaf(a4.z, b4.y, acc[2][1]);
            acc[2][2] = fmaf(a4.z, b4.z, acc[2][2]);
            acc[2][3] = fmaf(a4.z, b4.w, acc[2][3]);
            acc[3][0] = fmaf(a4.w, b4.x, acc[3][0]);
            acc[3][1] = fmaf(a4.w, b4.y, acc[3][1]);
            acc[3][2] = fmaf(a4.w, b4.z, acc[3][2]);
            acc[3][3] = fmaf(a4.w, b4.w, acc[3][3]);
        }
        __syncthreads();
    }
#pragma unroll
    for (int q = 0; q < 4; ++q) {
        float4 o;
        o.x = acc[q][0];
        o.y = acc[q][1];
        o.z = acc[q][2];
        o.w = acc[q][3];
        *(float4*)&C[(size_t)(m0 + (ty << 2) + q) * N + n0 + (tx << 2)] = o;
    }
}

// ---------------------------------------------------------------------------
// All 4 projection GEMMs in ONE launch (640 blocks).
// ---------------------------------------------------------------------------
__global__ __launch_bounds__(256) void gemms_all(
    const float* __restrict__ target, const float* __restrict__ context,
    const float* __restrict__ Wt, const float* __restrict__ bt,
    const float* __restrict__ Wc, const float* __restrict__ bc,
    const float* __restrict__ wct, const float* __restrict__ wcc,
    float* __restrict__ u, float* __restrict__ v,
    float* __restrict__ t64, float* __restrict__ c64) {
    __shared__ __align__(16) char smem[GEMM_SMEM_BYTES];
    const int bid = blockIdx.x;
    if (bid < 64) {
        gemm_f32_body(target, wct, t64, 4096, 64, 512, bid, 0, smem);
    } else if (bid < 128) {
        gemm_f32_body(context, wcc, c64, 4096, 64, 512, bid - 64, 0, smem);
    } else if (bid < 384) {
        const int r = bid - 128;
        gemm_bf16_body(target, Wt, bt, u, 4096, 512, 512, r & 31, r >> 5, smem);
    } else {
        const int r = bid - 384;
        gemm_bf16_body(context, Wc, bc, v, 4096, 512, 512, r & 31, r >> 5, smem);
    }
}

__global__ __launch_bounds__(256) void gemm_bf16(
    const float* __restrict__ A, const float* __restrict__ W,
    const float* __restrict__ bias, float* __restrict__ C,
    int M, int N, int Kd) {
    __shared__ __align__(16) char smem[GEMM_SMEM_BYTES];
    gemm_bf16_body(A, W, bias, C, M, N, Kd, blockIdx.x, blockIdx.y, smem);
}

// ---------------------------------------------------------------------------
// prep (144 blocks): 0..127 pack Ws1/Wa1/Wl1 -> wct/wcc [512,64];
//                    128..143 build Wl2bfT [4096 col][32 k] bf16, bl2 at k=16.
// ---------------------------------------------------------------------------
__global__ void prep_all(const float* __restrict__ Ws1, const float* __restrict__ Wa1,
                         const float* __restrict__ Wl1,
                         const float* __restrict__ Wl2, const float* __restrict__ bl2,
                         float* __restrict__ Wct, float* __restrict__ Wcc,
                         unsigned short* __restrict__ wl2bfT) {
    if (blockIdx.x < 128) {
        int idx = blockIdx.x * 256 + threadIdx.x;
        int k = idx >> 6, c = idx & 63;
        float vt = 0.f, vc = 0.f;
        if (c < 16)      { vt = Ws1[k * 16 + c];        vc = Ws1[(512 + k) * 16 + c]; }
        else if (c < 32) { vt = Wa1[k * 16 + (c - 16)]; vc = Wa1[(512 + k) * 16 + (c - 16)]; }
        else if (c < 48) { vt = Wl1[k * 16 + (c - 32)]; vc = Wl1[(512 + k) * 16 + (c - 32)]; }
        Wct[idx] = vt;
        Wcc[idx] = vc;
    } else {
        int c = (blockIdx.x - 128) * 256 + threadIdx.x;   // 0..4095
        union U8 { bf16x8s v; unsigned short s[8]; } r0, r1, r2, r3;
#pragma unroll
        for (int k = 0; k < 8; ++k) r0.s[k] = f2bf(Wl2[(size_t)k * 4096 + c]);
#pragma unroll
        for (int k = 0; k < 8; ++k) r1.s[k] = f2bf(Wl2[(size_t)(k + 8) * 4096 + c]);
#pragma unroll
        for (int k = 0; k < 8; ++k) { r2.s[k] = 0; r3.s[k] = 0; }
        r2.s[0] = f2bf(bl2[c]);   // bias row at k=16 (pairs with h16bf k16 = 1.0)
        unsigned short* dst = &wl2bfT[(size_t)c * 32];
        *(bf16x8s*)(dst + 0)  = r0.v;
        *(bf16x8s*)(dst + 8)  = r1.v;
        *(bf16x8s*)(dst + 16) = r2.v;
        *(bf16x8s*)(dst + 24) = r3.v;
    }
}

// ---------------------------------------------------------------------------
// Rotary table: rot[delta+2047][k] = (cos, sin) of (delta * 10000^(-k/32)).
// Runs AFTER edge_params — rot aliases t64, which is dead by then.
// ---------------------------------------------------------------------------
__global__ __launch_bounds__(256) void rot_prep(float* __restrict__ rot) {
    int idx = blockIdx.x * 256 + threadIdx.x;     // 0..131071
    int dlt = (idx >> 5) - 2047;
    int k = idx & 31;
    float invf = exp2f((float)k * (-13.287712379549449f / 32.0f));
    float s, c;
    sincosf((float)dlt * invf, &s, &c);
    ((float2*)rot)[idx] = make_float2(c, s);
}

// ---------------------------------------------------------------------------
// Fused scores + top-8 (tie-break: lowest index, matching jax.lax.top_k).
// 4 i-rows per block (1024 blocks): the c64 row is register-loaded ONCE and
// scored against 4 target rows -> L2 traffic on c64 cut 4x (the kernel was
// L2-BW bound, ~2 GB of re-reads). Per-row extraction unchanged (register-
// resident, low VGPR).
// ---------------------------------------------------------------------------
__global__ __launch_bounds__(256) void scores_topk(
    const float* __restrict__ t64, const float* __restrict__ c64,
    const float* __restrict__ bs1, const float* __restrict__ Ws2,
    const float* __restrict__ bs2, int* __restrict__ edge_j) {
    __shared__ float sc[4][KK];   // 32 KB
    __shared__ float wvs[4];
    __shared__ int wvj[4];
    const int tid = threadIdx.x;
    const int b = blockIdx.x >> 9;             // 512 blocks per batch
    const int i0 = (blockIdx.x & 511) << 2;    // 4 consecutive rows
    float tsb[4][16], w2[16];
#pragma unroll
    for (int k = 0; k < 16; ++k) w2[k] = Ws2[k];
#pragma unroll
    for (int g = 0; g < 4; ++g) {
        const float* tr = &t64[(size_t)(b * LL + i0 + g) * 64];
#pragma unroll
        for (int k = 0; k < 16; ++k) tsb[g][k] = tr[k] + bs1[k];
    }
    const float b2 = bs2[0];

    // Phase A: 4 score rows per c64 read
    for (int j = tid; j < KK; j += 256) {
        const float4* cr4 = (const float4*)&c64[(size_t)(b * KK + j) * 64];
        float creg[16];
        float4 c0 = cr4[0], c1 = cr4[1], c2 = cr4[2], c3 = cr4[3];
        creg[0] = c0.x; creg[1] = c0.y; creg[2] = c0.z; creg[3] = c0.w;
        creg[4] = c1.x; creg[5] = c1.y; creg[6] = c1.z; creg[7] = c1.w;
        creg[8] = c2.x; creg[9] = c2.y; creg[10] = c2.z; creg[11] = c2.w;
        creg[12] = c3.x; creg[13] = c3.y; creg[14] = c3.z; creg[15] = c3.w;
#pragma unroll
        for (int g = 0; g < 4; ++g) {
            float s = b2;
#pragma unroll
            for (int k = 0; k < 16; ++k)
                s = fmaf(gelu_f(tsb[g][k] + creg[k]), w2[k], s);
            sc[g][j] = s;
        }
    }
    __syncthreads();

    // Phase B: per-row register-resident extraction
    const int lane = tid & 63, wv = tid >> 6;
#pragma unroll
    for (int g = 0; g < 4; ++g) {
        float ls[8];
#pragma unroll
        for (int k = 0; k < 8; ++k) ls[k] = sc[g][tid + (k << 8)];
#pragma unroll
        for (int w = 0; w < WWIN; ++w) {
            float cs = ls[0];
            int ck = 0;
#pragma unroll
            for (int k = 1; k < 8; ++k)
                if (ls[k] > cs) { cs = ls[k]; ck = k; }
            int cj = tid + (ck << 8);
#pragma unroll
            for (int m = 1; m < 64; m <<= 1) {
                float os = __shfl_xor(cs, m);
                int oj = __shfl_xor(cj, m);
                if (os > cs || (os == cs && oj < cj)) { cs = os; cj = oj; }
            }
            if (lane == 0) { wvs[wv] = cs; wvj[wv] = cj; }
            __syncthreads();
            float bsv = wvs[0];
            int bjv = wvj[0];
#pragma unroll
            for (int q = 1; q < 4; ++q) {
                float qs = wvs[q];
                int qj = wvj[q];
                if (qs > bsv || (qs == bsv && qj < bjv)) { bsv = qs; bjv = qj; }
            }
            if (tid == 0) edge_j[(size_t)(b * LL + i0 + g) * WWIN + w] = bjv;
            {
                const bool own = (bjv & 255) == tid;
                const int bk = bjv >> 8;
#pragma unroll
                for (int k = 0; k < 8; ++k)
                    if (own && bk == k) ls[k] = -INFINITY;
            }
            __syncthreads();
        }
    }
}

// ---------------------------------------------------------------------------
// Per-edge params: h16bf (bf16, MFMA A-layout rows of 32 with k16=1.0) + alpha.
// ---------------------------------------------------------------------------
__global__ __launch_bounds__(256) void edge_params(
    const float* __restrict__ t64, const float* __restrict__ c64,
    const int* __restrict__ edge_j,
    const float* __restrict__ bl1, const float* __restrict__ ba1,
    const float* __restrict__ Wa2, const float* __restrict__ ba2,
    unsigned short* __restrict__ h16bf, float* __restrict__ alpha) {
    int idx = blockIdx.x * 256 + threadIdx.x;
    if (idx >= BB * NE) return;
    int b = idx >> 14;
    int i = (idx & (NE - 1)) >> 3;
    int j = edge_j[idx];
    const float* tr = &t64[(size_t)(b * LL + i) * 64];
    const float* cr = &c64[(size_t)(b * KK + j) * 64];
    union U8 { bf16x8s v; unsigned short s[8]; } o0, o1, o2, o3;
    float s = ba2[0];
#pragma unroll
    for (int k = 0; k < 8; ++k) {
        o0.s[k] = f2bf(gelu_f(tr[32 + k] + cr[32 + k] + bl1[k]));
        s = fmaf(gelu_f(tr[16 + k] + cr[16 + k] + ba1[k]), Wa2[k], s);
    }
#pragma unroll
    for (int k = 8; k < 16; ++k) {
        o1.s[k - 8] = f2bf(gelu_f(tr[32 + k] + cr[32 + k] + bl1[k]));
        s = fmaf(gelu_f(tr[16 + k] + cr[16 + k] + ba1[k]), Wa2[k], s);
    }
#pragma unroll
    for (int k = 0; k < 8; ++k) { o2.s[k] = 0; o3.s[k] = 0; }
    o2.s[0] = 0x3F80;   // bf16(1.0) at k=16: multiplies Wl2bfT's bl2 row
    unsigned short* dst = &h16bf[(size_t)idx * 32];
    *(bf16x8s*)(dst + 0)  = o0.v;
    *(bf16x8s*)(dst + 8)  = o1.v;
    *(bf16x8s*)(dst + 16) = o2.v;
    *(bf16x8s*)(dst + 24) = o3.v;
    alpha[idx] = softplus_f(s);
}

// ---------------------------------------------------------------------------
// Fused T=2 consensus iterations — EXACTLY R8's kernel.
// __launch_bounds__(256,3): (256,4) in R10 forced VGPR 76->64, spilling
// lamr[8][8] to scratch (FETCH 10MB->102MB, dur 124->141). 3 blocks/CU with
// lamr register-resident is the proven optimum.
// ---------------------------------------------------------------------------
__global__ __launch_bounds__(256, 3) void iterate_k(
    float* __restrict__ u, const float* __restrict__ v,
    const int* __restrict__ edge_j, const float* __restrict__ alpha,
    const unsigned short* __restrict__ h16bf,
    const unsigned short* __restrict__ wl2bfT,
    const float* __restrict__ rotT,
    const float* __restrict__ step_sizes) {
    __shared__ unsigned short lam_s[32 * 520];   // [edge][d*8 + r], pad 8/row
    __shared__ float alphs[32];
    __shared__ int ejs[32];
    __shared__ float dts[4][64];
    const int tid = threadIdx.x;
    const int h = blockIdx.y, b = blockIdx.z;
    const int i0 = blockIdx.x << 2;
    const int e0 = b * NE + (i0 << 3);

    if (tid < 32) { ejs[tid] = edge_j[e0 + tid]; alphs[tid] = alpha[e0 + tid]; }

    const int wv = tid >> 6, lane = tid & 63;
    const int l15 = lane & 15, lg = lane >> 4;

    // ---- Phase 1: Lam via MFMA, packed b64 write-out ----
    {
        const int mt = wv & 1;
        const int rbase = (wv >> 1) << 2;
        bf16x8s afrag = *(const bf16x8s*)&h16bf[(size_t)(e0 + (mt << 4) + l15) * 32 + (lg << 3)];
        const unsigned short* wbase = &wl2bfT[((size_t)(h * 512 + (rbase << 6) + l15)) * 32 + (lg << 3)];
#pragma unroll
        for (int g = 0; g < 4; ++g) {
            f32x4 a0 = {0.f, 0.f, 0.f, 0.f}, a1 = a0, a2 = a0, a3 = a0;
            const unsigned short* wg = wbase + g * 512;   // +16 cols
            a0 = __builtin_amdgcn_mfma_f32_16x16x32_bf16(afrag, *(const bf16x8s*)(wg + 0),    a0, 0, 0, 0);
            a1 = __builtin_amdgcn_mfma_f32_16x16x32_bf16(afrag, *(const bf16x8s*)(wg + 2048), a1, 0, 0, 0);
            a2 = __builtin_amdgcn_mfma_f32_16x16x32_bf16(afrag, *(const bf16x8s*)(wg + 4096), a2, 0, 0, 0);
            a3 = __builtin_amdgcn_mfma_f32_16x16x32_bf16(afrag, *(const bf16x8s*)(wg + 6144), a3, 0, 0, 0);
            const int d = (g << 4) + l15;
#pragma unroll
            for (int j = 0; j < 4; ++j) {
                const int e = (mt << 4) + (lg << 2) + j;
                uint2 pk;
                pk.x = (unsigned int)f2bf(a0[j]) | ((unsigned int)f2bf(a1[j]) << 16);
                pk.y = (unsigned int)f2bf(a2[j]) | ((unsigned int)f2bf(a3[j]) << 16);
                *(uint2*)&lam_s[e * 520 + (d << 3) + rbase] = pk;
            }
        }
    }
    __syncthreads();

    const int i = i0 + wv;
    const size_t urow = ((size_t)(b * LL + i)) * DD + h * HD_ + lane;
    float u_d = u[urow];
    const float st0 = softplus_f(step_sizes[i]);
    const float st1 = softplus_f(step_sizes[LL + i]);

    const bool up32 = (lane & 32) != 0;
    const bool up16 = (lane & 16) != 0;
    const bool up8  = (lane & 8) != 0;
    const bool up4  = (lane & 4) != 0;
    const bool up2  = (lane & 2) != 0;
    const bool up1  = (lane & 1) != 0;

    // read back own 8 edges: lamr[w][r], lane = d (8x ds_read_b128)
    float lamr[8][8];
#pragma unroll
    for (int w = 0; w < 8; ++w) {
        union U8 { bf16x8s v; unsigned short s[8]; } lv;
        lv.v = *(const bf16x8s*)&lam_s[((wv << 3) + w) * 520 + (lane << 3)];
#pragma unroll
        for (int r = 0; r < 8; ++r) lamr[w][r] = bf2f(lv.s[r]);
    }

    // ss reduce-scatter (xor-32 fused into build); inv_ss lands on lane idx
    float inv_ss;
    {
        float q[32];
#pragma unroll
        for (int wp = 0; wp < 4; ++wp)
#pragma unroll
            for (int r = 0; r < 8; ++r) {
                float plo = lamr[wp][r] * lamr[wp][r];
                float phi = lamr[wp + 4][r] * lamr[wp + 4][r];
                float recv = __shfl_xor(up32 ? plo : phi, 32);
                q[(wp << 3) + r] = (up32 ? phi : plo) + recv;
            }
#pragma unroll
        for (int j = 0; j < 16; ++j) {
            float lo = q[j], hi = q[j + 16];
            float recv = __shfl_xor(up16 ? lo : hi, 16);
            q[j] = (up16 ? hi : lo) + recv;
        }
#pragma unroll
        for (int j = 0; j < 8; ++j) {
            float lo = q[j], hi = q[j + 8];
            float recv = __shfl_xor(up8 ? lo : hi, 8);
            q[j] = (up8 ? hi : lo) + recv;
        }
#pragma unroll
        for (int j = 0; j < 4; ++j) {
            float lo = q[j], hi = q[j + 4];
            float recv = __shfl_xor(up4 ? lo : hi, 4);
            q[j] = (up4 ? hi : lo) + recv;
        }
#pragma unroll
        for (int j = 0; j < 2; ++j) {
            float lo = q[j], hi = q[j + 2];
            float recv = __shfl_xor(up2 ? lo : hi, 2);
            q[j] = (up2 ? hi : lo) + recv;
        }
        {
            float lo = q[0], hi = q[1];
            float recv = __shfl_xor(up1 ? lo : hi, 1);
            q[0] = (up1 ? hi : lo) + recv;
        }
        inv_ss = 1.0f / fmaxf(q[0], 1e-24f);
    }

    // Phase 2: per-edge v rows, rotary cos/sin (table), alpha
    const int k31 = lane & 31;
    float vw[8], cw[8], sw[8], aw[8];
#pragma unroll
    for (int w = 0; w < 8; ++w) {
        const int le = (wv << 3) + w;
        const int j = ejs[le];
        aw[w] = alphs[le];
        vw[w] = v[((size_t)(b * KK + j)) * DD + h * HD_ + lane];
        float2 rc = ((const float2*)rotT)[((size_t)(i - j + 2047) << 5) + k31];
        cw[w] = rc.x;
        sw[w] = rc.y;
    }

#pragma unroll
    for (int t = 0; t < 2; ++t) {
        float upv = __shfl_xor(u_d, 32);
        float rotb = (lane < 32) ? -upv : upv;   // rotate_half
        float resid = 0.0f;
        float q[32];
#pragma unroll
        for (int wp = 0; wp < 4; ++wp) {
            float dlo = fmaf(u_d, cw[wp], rotb * sw[wp]) - vw[wp];
            float dhi = fmaf(u_d, cw[wp + 4], rotb * sw[wp + 4]) - vw[wp + 4];
            resid = fmaf(aw[wp], dlo, resid);
            resid = fmaf(aw[wp + 4], dhi, resid);
#pragma unroll
            for (int r = 0; r < 8; ++r) {
                float plo = lamr[wp][r] * dlo;
                float phi = lamr[wp + 4][r] * dhi;
                float recv = __shfl_xor(up32 ? plo : phi, 32);
                q[(wp << 3) + r] = (up32 ? phi : plo) + recv;
            }
        }
#pragma unroll
        for (int j = 0; j < 16; ++j) {
            float lo = q[j], hi = q[j + 16];
            float recv = __shfl_xor(up16 ? lo : hi, 16);
            q[j] = (up16 ? hi : lo) + recv;
        }
#pragma unroll
        for (int j = 0; j < 8; ++j) {
            float lo = q[j], hi = q[j + 8];
            float recv = __shfl_xor(up8 ? lo : hi, 8);
            q[j] = (up8 ? hi : lo) + recv;
        }
#pragma unroll
        for (int j = 0; j < 4; ++j) {
            float lo = q[j], hi = q[j + 4];
            float recv = __shfl_xor(up4 ? lo : hi, 4);
            q[j] = (up4 ? hi : lo) + recv;
        }
#pragma unroll
        for (int j = 0; j < 2; ++j) {
            float lo = q[j], hi = q[j + 2];
            float recv = __shfl_xor(up2 ? lo : hi, 2);
            q[j] = (up2 ? hi : lo) + recv;
        }
        {
            float lo = q[0], hi = q[1];
            float recv = __shfl_xor(up1 ? lo : hi, 1);
            q[0] = (up1 ? hi : lo) + recv;
        }
        // dt/ss for (w=lane>>3, r=lane&7) sits on lane; share via LDS
        dts[wv][lane] = q[0] * inv_ss;
#pragma unroll
        for (int w = 0; w < 8; ++w) {
            float4 da = *(const float4*)&dts[wv][(w << 3)];
            float4 db = *(const float4*)&dts[wv][(w << 3) + 4];
            resid = fmaf(da.x, lamr[w][0], resid);
            resid = fmaf(da.y, lamr[w][1], resid);
            resid = fmaf(da.z, lamr[w][2], resid);
            resid = fmaf(da.w, lamr[w][3], resid);
            resid = fmaf(db.x, lamr[w][4], resid);
            resid = fmaf(db.y, lamr[w][5], resid);
            resid = fmaf(db.z, lamr[w][6], resid);
            resid = fmaf(db.w, lamr[w][7], resid);
        }
        u_d = fmaf((t == 0) ? -st0 : -st1, resid, u_d);
    }
    u[urow] = u_d;
}

// ---------------------------------------------------------------------------
extern "C" void kernel_launch(void* const* d_in, const int* in_sizes, int n_in,
                              void* d_out, int out_size, void* d_ws, size_t ws_size,
                              hipStream_t stream) {
    (void)in_sizes; (void)n_in; (void)out_size; (void)ws_size;
    const float* target     = (const float*)d_in[0];
    const float* context    = (const float*)d_in[1];
    const float* Wt         = (const float*)d_in[2];
    const float* bt         = (const float*)d_in[3];
    const float* Wc         = (const float*)d_in[4];
    const float* bc         = (const float*)d_in[5];
    const float* Ws1        = (const float*)d_in[6];
    const float* bs1        = (const float*)d_in[7];
    const float* Ws2        = (const float*)d_in[8];
    const float* bs2        = (const float*)d_in[9];
    const float* Wa1        = (const float*)d_in[10];
    const float* ba1        = (const float*)d_in[11];
    const float* Wa2        = (const float*)d_in[12];
    const float* ba2        = (const float*)d_in[13];
    const float* Wl1        = (const float*)d_in[14];
    const float* bl1        = (const float*)d_in[15];
    const float* Wl2        = (const float*)d_in[16];
    const float* bl2        = (const float*)d_in[17];
    const float* step_sizes = (const float*)d_in[18];
    const float* Wo         = (const float*)d_in[19];
    const float* bo         = (const float*)d_in[20];
    float* out = (float*)d_out;

    // Workspace layout (floats). NOTE: h16bf is 32768 edges * 32 hw
    // = 1048576 hw = 524288 floats -> occupies [4718592, 5242880).
    float* ws = (float*)d_ws;
    float* u    = ws;                               // [0, 2097152)
    float* v    = ws + 2097152;                     // [2097152, 4194304)
    float* t64  = ws + 4194304;                     // [4194304, 4456448) (reused as rotT)
    float* c64  = ws + 4456448;                     // [4456448, 4718592)
    unsigned short* h16bf = (unsigned short*)(ws + 4718592);  // [4718592, 5242880)
    float* alph = ws + 5242880;                     // [5242880, 5275648)
    int*   ej   = (int*)(ws + 5275648);             // [5275648, 5308416)
    float* wct  = ws + 5308416;                     // [5308416, 5341184)
    float* wcc  = ws + 5341184;                     // [5341184, 5373952)
    unsigned short* wl2bfT = (unsigned short*)(ws + 5373952); // [5373952, 5439488)
    float* rotT = t64;   // rotary table aliases t64 AFTER edge_params (t64 dead)

    prep_all<<<dim3(144), dim3(256), 0, stream>>>(
        Ws1, Wa1, Wl1, Wl2, bl2, wct, wcc, wl2bfT);

    gemms_all<<<dim3(640), dim3(256), 0, stream>>>(
        target, context, Wt, bt, Wc, bc, wct, wcc, u, v, t64, c64);

    scores_topk<<<dim3(BB * LL / 4), dim3(256), 0, stream>>>(t64, c64, bs1, Ws2, bs2, ej);

    edge_params<<<dim3(BB * NE / 256), dim3(256), 0, stream>>>(t64, c64, ej, bl1, ba1, Wa2, ba2, h16bf, alph);

    rot_prep<<<dim3(512), dim3(256), 0, stream>>>(rotT);   // overwrites t64 (dead)

    iterate_k<<<dim3(LL / 4, HH, BB), dim3(256), 0, stream>>>(u, v, ej, alph, h16bf, wl2bfT, rotT, step_sizes);

    gemm_bf16<<<dim3(32, 8), dim3(256), 0, stream>>>(u, Wo, bo, out, 4096, 512, 512);
}

// Round 12
// 286.900 us; speedup vs baseline: 1.2103x; 1.2103x over previous
//
#include <hip/hip_runtime.h>
#include <math.h>

// Problem constants
#define BB 2
#define LL 2048
#define KK 2048
#define DD 512
#define HH 8
#define HD_ 64
#define RR 8
#define WWIN 8
#define NE (LL * WWIN)   // 16384 edges per batch

typedef __attribute__((ext_vector_type(8))) short bf16x8s;
typedef __attribute__((ext_vector_type(4))) float f32x4;

__device__ __forceinline__ float gelu_f(float x) {
    return 0.5f * x * (1.0f + erff(x * 0.70710678118654752f));
}
__device__ __forceinline__ float softplus_f(float x) {
    return (x > 20.0f) ? x : log1pf(expf(x));
}
__device__ __forceinline__ unsigned short f2bf(float f) {
    unsigned int x = __float_as_uint(f);
    x += 0x7FFFu + ((x >> 16) & 1u);   // RTNE
    return (unsigned short)(x >> 16);
}
__device__ __forceinline__ float bf2f(unsigned short s) {
    return __uint_as_float(((unsigned int)s) << 16);
}

#define GEMM_SMEM_BYTES 15360   // max(bf16: 10240+5120, f32: 4352+4352)

// ---------------------------------------------------------------------------
// bf16-MFMA GEMM body: C[M,N] = A[M,Kd]@W[Kd,N] (+bias), f32 in/out.
// Tile 128x64, BK=32, 4 waves (2M x 2N), wave tile 64x32, frags 4x2 of 16x16.
// ---------------------------------------------------------------------------
__device__ __forceinline__ void gemm_bf16_body(
    const float* __restrict__ A, const float* __restrict__ W,
    const float* __restrict__ bias, float* __restrict__ C,
    int M, int N, int Kd, int bx, int by, char* smem) {
    short (*As)[40] = (short(*)[40])smem;
    short (*Bs)[40] = (short(*)[40])(smem + 128 * 40 * 2);
    const int tid = threadIdx.x;
    const int m0 = bx * 128, n0 = by * 64;
    const int wv = tid >> 6, lane = tid & 63;
    const int wm = (wv & 1) << 6, wn = (wv >> 1) << 5;
    const int l15 = lane & 15, lg = lane >> 4;

    f32x4 acc[4][2] = {};
    union S8 { bf16x8s v; short s[8]; };

    const int arow = tid >> 1, akh = (tid & 1) << 4;
    const int bk = tid >> 3, bnb = (tid & 7) << 3;

    for (int k0 = 0; k0 < Kd; k0 += 32) {
        {
            const float* ap = &A[(size_t)(m0 + arow) * Kd + k0 + akh];
            float4 f0 = *(const float4*)(ap + 0);
            float4 f1 = *(const float4*)(ap + 4);
            float4 f2 = *(const float4*)(ap + 8);
            float4 f3 = *(const float4*)(ap + 12);
            S8 s0, s1;
            s0.s[0] = f2bf(f0.x); s0.s[1] = f2bf(f0.y); s0.s[2] = f2bf(f0.z); s0.s[3] = f2bf(f0.w);
            s0.s[4] = f2bf(f1.x); s0.s[5] = f2bf(f1.y); s0.s[6] = f2bf(f1.z); s0.s[7] = f2bf(f1.w);
            s1.s[0] = f2bf(f2.x); s1.s[1] = f2bf(f2.y); s1.s[2] = f2bf(f2.z); s1.s[3] = f2bf(f2.w);
            s1.s[4] = f2bf(f3.x); s1.s[5] = f2bf(f3.y); s1.s[6] = f2bf(f3.z); s1.s[7] = f2bf(f3.w);
            *(bf16x8s*)&As[arow][akh] = s0.v;
            *(bf16x8s*)&As[arow][akh + 8] = s1.v;
        }
        {
            const float* wp = &W[(size_t)(k0 + bk) * N + n0 + bnb];
            float4 w0 = *(const float4*)(wp + 0);
            float4 w1 = *(const float4*)(wp + 4);
            Bs[bnb + 0][bk] = f2bf(w0.x);
            Bs[bnb + 1][bk] = f2bf(w0.y);
            Bs[bnb + 2][bk] = f2bf(w0.z);
            Bs[bnb + 3][bk] = f2bf(w0.w);
            Bs[bnb + 4][bk] = f2bf(w1.x);
            Bs[bnb + 5][bk] = f2bf(w1.y);
            Bs[bnb + 6][bk] = f2bf(w1.z);
            Bs[bnb + 7][bk] = f2bf(w1.w);
        }
        __syncthreads();
        bf16x8s af[4], bf[2];
#pragma unroll
        for (int mf = 0; mf < 4; ++mf)
            af[mf] = *(const bf16x8s*)&As[wm + (mf << 4) + l15][lg << 3];
#pragma unroll
        for (int nf = 0; nf < 2; ++nf)
            bf[nf] = *(const bf16x8s*)&Bs[wn + (nf << 4) + l15][lg << 3];
#pragma unroll
        for (int mf = 0; mf < 4; ++mf)
#pragma unroll
            for (int nf = 0; nf < 2; ++nf)
                acc[mf][nf] = __builtin_amdgcn_mfma_f32_16x16x32_bf16(af[mf], bf[nf], acc[mf][nf], 0, 0, 0);
        __syncthreads();
    }
    float bv[2] = {0.f, 0.f};
    if (bias) {
        bv[0] = bias[n0 + wn + l15];
        bv[1] = bias[n0 + wn + 16 + l15];
    }
#pragma unroll
    for (int mf = 0; mf < 4; ++mf)
#pragma unroll
        for (int nf = 0; nf < 2; ++nf)
#pragma unroll
            for (int j = 0; j < 4; ++j) {
                int crow = m0 + wm + (mf << 4) + (lg << 2) + j;
                int ccol = n0 + wn + (nf << 4) + l15;
                C[(size_t)crow * N + ccol] = acc[mf][nf][j] + bv[nf];
            }
}

// ---------------------------------------------------------------------------
// f32 GEMM body (kept for t64/c64: exact scores -> stable top-k).
// ---------------------------------------------------------------------------
__device__ __forceinline__ void gemm_f32_body(
    const float* __restrict__ A, const float* __restrict__ W,
    float* __restrict__ C, int M, int N, int Kd, int bx, int by, char* smem) {
    float (*As)[68] = (float(*)[68])smem;
    float (*Bs)[68] = (float(*)[68])(smem + 16 * 68 * 4);
    const int tid = threadIdx.x;
    const int m0 = bx * 64, n0 = by * 64;
    const int tx = tid & 15, ty = tid >> 4;
    const int row_a = tid >> 2, kq_a = (tid & 3) << 2;
    const int kw = tid >> 4, nq = (tid & 15) << 2;
    float acc[4][4] = {};
    for (int k0 = 0; k0 < Kd; k0 += 16) {
        float4 av = *(const float4*)&A[(size_t)(m0 + row_a) * Kd + k0 + kq_a];
        As[kq_a + 0][row_a] = av.x;
        As[kq_a + 1][row_a] = av.y;
        As[kq_a + 2][row_a] = av.z;
        As[kq_a + 3][row_a] = av.w;
        *(float4*)&Bs[kw][nq] = *(const float4*)&W[(size_t)(k0 + kw) * N + n0 + nq];
        __syncthreads();
#pragma unroll
        for (int k = 0; k < 16; ++k) {
            float4 a4 = *(const float4*)&As[k][ty << 2];
            float4 b4 = *(const float4*)&Bs[k][tx << 2];
            acc[0][0] = fmaf(a4.x, b4.x, acc[0][0]);
            acc[0][1] = fmaf(a4.x, b4.y, acc[0][1]);
            acc[0][2] = fmaf(a4.x, b4.z, acc[0][2]);
            acc[0][3] = fmaf(a4.x, b4.w, acc[0][3]);
            acc[1][0] = fmaf(a4.y, b4.x, acc[1][0]);
            acc[1][1] = fmaf(a4.y, b4.y, acc[1][1]);
            acc[1][2] = fmaf(a4.y, b4.z, acc[1][2]);
            acc[1][3] = fmaf(a4.y, b4.w, acc[1][3]);
            acc[2][0] = fmaf(a4.z, b4.x, acc[2][0]);
            acc[2][1] = fmaf(a4.z, b4.y, acc[2][1]);
            acc[2][2] = fmaf(a4.z, b4.z, acc[2][2]);
            acc[2][3] = fmaf(a4.z, b4.w, acc[2][3]);
            acc[3][0] = fmaf(a4.w, b4.x, acc[3][0]);
            acc[3][1] = fmaf(a4.w, b4.y, acc[3][1]);
            acc[3][2] = fmaf(a4.w, b4.z, acc[3][2]);
            acc[3][3] = fmaf(a4.w, b4.w, acc[3][3]);
        }
        __syncthreads();
    }
#pragma unroll
    for (int q = 0; q < 4; ++q) {
        float4 o;
        o.x = acc[q][0];
        o.y = acc[q][1];
        o.z = acc[q][2];
        o.w = acc[q][3];
        *(float4*)&C[(size_t)(m0 + (ty << 2) + q) * N + n0 + (tx << 2)] = o;
    }
}

// ---------------------------------------------------------------------------
// All 4 projection GEMMs in ONE launch (640 blocks).
// ---------------------------------------------------------------------------
__global__ __launch_bounds__(256) void gemms_all(
    const float* __restrict__ target, const float* __restrict__ context,
    const float* __restrict__ Wt, const float* __restrict__ bt,
    const float* __restrict__ Wc, const float* __restrict__ bc,
    const float* __restrict__ wct, const float* __restrict__ wcc,
    float* __restrict__ u, float* __restrict__ v,
    float* __restrict__ t64, float* __restrict__ c64) {
    __shared__ __align__(16) char smem[GEMM_SMEM_BYTES];
    const int bid = blockIdx.x;
    if (bid < 64) {
        gemm_f32_body(target, wct, t64, 4096, 64, 512, bid, 0, smem);
    } else if (bid < 128) {
        gemm_f32_body(context, wcc, c64, 4096, 64, 512, bid - 64, 0, smem);
    } else if (bid < 384) {
        const int r = bid - 128;
        gemm_bf16_body(target, Wt, bt, u, 4096, 512, 512, r & 31, r >> 5, smem);
    } else {
        const int r = bid - 384;
        gemm_bf16_body(context, Wc, bc, v, 4096, 512, 512, r & 31, r >> 5, smem);
    }
}

__global__ __launch_bounds__(256) void gemm_bf16(
    const float* __restrict__ A, const float* __restrict__ W,
    const float* __restrict__ bias, float* __restrict__ C,
    int M, int N, int Kd) {
    __shared__ __align__(16) char smem[GEMM_SMEM_BYTES];
    gemm_bf16_body(A, W, bias, C, M, N, Kd, blockIdx.x, blockIdx.y, smem);
}

// ---------------------------------------------------------------------------
// prep (656 blocks, one launch, runs FIRST):
//  blocks 0..127   pack Ws1/Wa1/Wl1 -> wct/wcc [512,64]
//  blocks 128..143 build Wl2bfT [4096 col][32 k] bf16, bl2 at k=16
//  blocks 144..655 rotary table rot[delta+2047][k31] -> d_out scratch region
//                  (d_out is only written by the FINAL gemm, after iterate_k
//                  has consumed the table — safe, deterministic, re-written
//                  every call).
// ---------------------------------------------------------------------------
__global__ void prep_all(const float* __restrict__ Ws1, const float* __restrict__ Wa1,
                         const float* __restrict__ Wl1,
                         const float* __restrict__ Wl2, const float* __restrict__ bl2,
                         float* __restrict__ Wct, float* __restrict__ Wcc,
                         unsigned short* __restrict__ wl2bfT,
                         float* __restrict__ rot) {
    if (blockIdx.x < 128) {
        int idx = blockIdx.x * 256 + threadIdx.x;
        int k = idx >> 6, c = idx & 63;
        float vt = 0.f, vc = 0.f;
        if (c < 16)      { vt = Ws1[k * 16 + c];        vc = Ws1[(512 + k) * 16 + c]; }
        else if (c < 32) { vt = Wa1[k * 16 + (c - 16)]; vc = Wa1[(512 + k) * 16 + (c - 16)]; }
        else if (c < 48) { vt = Wl1[k * 16 + (c - 32)]; vc = Wl1[(512 + k) * 16 + (c - 32)]; }
        Wct[idx] = vt;
        Wcc[idx] = vc;
    } else if (blockIdx.x < 144) {
        int c = (blockIdx.x - 128) * 256 + threadIdx.x;   // 0..4095
        union U8 { bf16x8s v; unsigned short s[8]; } r0, r1, r2, r3;
#pragma unroll
        for (int k = 0; k < 8; ++k) r0.s[k] = f2bf(Wl2[(size_t)k * 4096 + c]);
#pragma unroll
        for (int k = 0; k < 8; ++k) r1.s[k] = f2bf(Wl2[(size_t)(k + 8) * 4096 + c]);
#pragma unroll
        for (int k = 0; k < 8; ++k) { r2.s[k] = 0; r3.s[k] = 0; }
        r2.s[0] = f2bf(bl2[c]);   // bias row at k=16 (pairs with h16bf k16 = 1.0)
        unsigned short* dst = &wl2bfT[(size_t)c * 32];
        *(bf16x8s*)(dst + 0)  = r0.v;
        *(bf16x8s*)(dst + 8)  = r1.v;
        *(bf16x8s*)(dst + 16) = r2.v;
        *(bf16x8s*)(dst + 24) = r3.v;
    } else {
        int idx = (blockIdx.x - 144) * 256 + threadIdx.x;   // 0..131071
        int dlt = (idx >> 5) - 2047;
        int k = idx & 31;
        float invf = exp2f((float)k * (-13.287712379549449f / 32.0f));
        float s, c;
        sincosf((float)dlt * invf, &s, &c);
        ((float2*)rot)[idx] = make_float2(c, s);
    }
}

// ---------------------------------------------------------------------------
// Fused scores + top-8 — EXACTLY R8's kernel (1 row/block, 4096 blocks).
// R11's 4-row variant regressed (176us, occupancy 25.6%): the kernel is
// compute/latency bound, not L2-BW bound; high block count is the win.
// ---------------------------------------------------------------------------
__global__ __launch_bounds__(256) void scores_topk(
    const float* __restrict__ t64, const float* __restrict__ c64,
    const float* __restrict__ bs1, const float* __restrict__ Ws2,
    const float* __restrict__ bs2, int* __restrict__ edge_j) {
    __shared__ float sc[KK];
    __shared__ float wvs[4];
    __shared__ int wvj[4];
    const int tid = threadIdx.x;
    const int b = blockIdx.x >> 11;
    const int i = blockIdx.x & (LL - 1);
    float tsb[16], w2[16];
    const float* tr = &t64[(size_t)(b * LL + i) * 64];
#pragma unroll
    for (int k = 0; k < 16; ++k) { tsb[k] = tr[k] + bs1[k]; w2[k] = Ws2[k]; }
    const float b2 = bs2[0];
    for (int j = tid; j < KK; j += 256) {
        const float4* cr4 = (const float4*)&c64[(size_t)(b * KK + j) * 64];
        float creg[16];
        float4 c0 = cr4[0], c1 = cr4[1], c2 = cr4[2], c3 = cr4[3];
        creg[0] = c0.x; creg[1] = c0.y; creg[2] = c0.z; creg[3] = c0.w;
        creg[4] = c1.x; creg[5] = c1.y; creg[6] = c1.z; creg[7] = c1.w;
        creg[8] = c2.x; creg[9] = c2.y; creg[10] = c2.z; creg[11] = c2.w;
        creg[12] = c3.x; creg[13] = c3.y; creg[14] = c3.z; creg[15] = c3.w;
        float s = b2;
#pragma unroll
        for (int k = 0; k < 16; ++k)
            s = fmaf(gelu_f(tsb[k] + creg[k]), w2[k], s);
        sc[j] = s;
    }
    __syncthreads();

    float ls[8];
#pragma unroll
    for (int k = 0; k < 8; ++k) ls[k] = sc[tid + (k << 8)];
    const int lane = tid & 63, wv = tid >> 6;
#pragma unroll
    for (int w = 0; w < WWIN; ++w) {
        float cs = ls[0];
        int ck = 0;
#pragma unroll
        for (int k = 1; k < 8; ++k)
            if (ls[k] > cs) { cs = ls[k]; ck = k; }
        int cj = tid + (ck << 8);
#pragma unroll
        for (int m = 1; m < 64; m <<= 1) {
            float os = __shfl_xor(cs, m);
            int oj = __shfl_xor(cj, m);
            if (os > cs || (os == cs && oj < cj)) { cs = os; cj = oj; }
        }
        if (lane == 0) { wvs[wv] = cs; wvj[wv] = cj; }
        __syncthreads();
        float bsv = wvs[0];
        int bjv = wvj[0];
#pragma unroll
        for (int q = 1; q < 4; ++q) {
            float qs = wvs[q];
            int qj = wvj[q];
            if (qs > bsv || (qs == bsv && qj < bjv)) { bsv = qs; bjv = qj; }
        }
        if (tid == 0) edge_j[(size_t)(b * LL + i) * WWIN + w] = bjv;
        {
            const bool own = (bjv & 255) == tid;
            const int bk = bjv >> 8;
#pragma unroll
            for (int k = 0; k < 8; ++k)
                if (own && bk == k) ls[k] = -INFINITY;
        }
        __syncthreads();
    }
}

// ---------------------------------------------------------------------------
// Per-edge params: h16bf (bf16, MFMA A-layout rows of 32 with k16=1.0) + alpha.
// ---------------------------------------------------------------------------
__global__ __launch_bounds__(256) void edge_params(
    const float* __restrict__ t64, const float* __restrict__ c64,
    const int* __restrict__ edge_j,
    const float* __restrict__ bl1, const float* __restrict__ ba1,
    const float* __restrict__ Wa2, const float* __restrict__ ba2,
    unsigned short* __restrict__ h16bf, float* __restrict__ alpha) {
    int idx = blockIdx.x * 256 + threadIdx.x;
    if (idx >= BB * NE) return;
    int b = idx >> 14;
    int i = (idx & (NE - 1)) >> 3;
    int j = edge_j[idx];
    const float* tr = &t64[(size_t)(b * LL + i) * 64];
    const float* cr = &c64[(size_t)(b * KK + j) * 64];
    union U8 { bf16x8s v; unsigned short s[8]; } o0, o1, o2, o3;
    float s = ba2[0];
#pragma unroll
    for (int k = 0; k < 8; ++k) {
        o0.s[k] = f2bf(gelu_f(tr[32 + k] + cr[32 + k] + bl1[k]));
        s = fmaf(gelu_f(tr[16 + k] + cr[16 + k] + ba1[k]), Wa2[k], s);
    }
#pragma unroll
    for (int k = 8; k < 16; ++k) {
        o1.s[k - 8] = f2bf(gelu_f(tr[32 + k] + cr[32 + k] + bl1[k]));
        s = fmaf(gelu_f(tr[16 + k] + cr[16 + k] + ba1[k]), Wa2[k], s);
    }
#pragma unroll
    for (int k = 0; k < 8; ++k) { o2.s[k] = 0; o3.s[k] = 0; }
    o2.s[0] = 0x3F80;   // bf16(1.0) at k=16: multiplies Wl2bfT's bl2 row
    unsigned short* dst = &h16bf[(size_t)idx * 32];
    *(bf16x8s*)(dst + 0)  = o0.v;
    *(bf16x8s*)(dst + 8)  = o1.v;
    *(bf16x8s*)(dst + 16) = o2.v;
    *(bf16x8s*)(dst + 24) = o3.v;
    alpha[idx] = softplus_f(s);
}

// ---------------------------------------------------------------------------
// Fused T=2 consensus iterations — EXACTLY R8's kernel.
// (256,3): R10's (256,4) forced VGPR 76->64, spilling lamr[8][8] to scratch
// (FETCH 10MB->102MB, dur 124->141). 3 blocks/CU, lamr register-resident.
// ---------------------------------------------------------------------------
__global__ __launch_bounds__(256, 3) void iterate_k(
    float* __restrict__ u, const float* __restrict__ v,
    const int* __restrict__ edge_j, const float* __restrict__ alpha,
    const unsigned short* __restrict__ h16bf,
    const unsigned short* __restrict__ wl2bfT,
    const float* __restrict__ rotT,
    const float* __restrict__ step_sizes) {
    __shared__ unsigned short lam_s[32 * 520];   // [edge][d*8 + r], pad 8/row
    __shared__ float alphs[32];
    __shared__ int ejs[32];
    __shared__ float dts[4][64];
    const int tid = threadIdx.x;
    const int h = blockIdx.y, b = blockIdx.z;
    const int i0 = blockIdx.x << 2;
    const int e0 = b * NE + (i0 << 3);

    if (tid < 32) { ejs[tid] = edge_j[e0 + tid]; alphs[tid] = alpha[e0 + tid]; }

    const int wv = tid >> 6, lane = tid & 63;
    const int l15 = lane & 15, lg = lane >> 4;

    // ---- Phase 1: Lam via MFMA, packed b64 write-out ----
    {
        const int mt = wv & 1;
        const int rbase = (wv >> 1) << 2;
        bf16x8s afrag = *(const bf16x8s*)&h16bf[(size_t)(e0 + (mt << 4) + l15) * 32 + (lg << 3)];
        const unsigned short* wbase = &wl2bfT[((size_t)(h * 512 + (rbase << 6) + l15)) * 32 + (lg << 3)];
#pragma unroll
        for (int g = 0; g < 4; ++g) {
            f32x4 a0 = {0.f, 0.f, 0.f, 0.f}, a1 = a0, a2 = a0, a3 = a0;
            const unsigned short* wg = wbase + g * 512;   // +16 cols
            a0 = __builtin_amdgcn_mfma_f32_16x16x32_bf16(afrag, *(const bf16x8s*)(wg + 0),    a0, 0, 0, 0);
            a1 = __builtin_amdgcn_mfma_f32_16x16x32_bf16(afrag, *(const bf16x8s*)(wg + 2048), a1, 0, 0, 0);
            a2 = __builtin_amdgcn_mfma_f32_16x16x32_bf16(afrag, *(const bf16x8s*)(wg + 4096), a2, 0, 0, 0);
            a3 = __builtin_amdgcn_mfma_f32_16x16x32_bf16(afrag, *(const bf16x8s*)(wg + 6144), a3, 0, 0, 0);
            const int d = (g << 4) + l15;
#pragma unroll
            for (int j = 0; j < 4; ++j) {
                const int e = (mt << 4) + (lg << 2) + j;
                uint2 pk;
                pk.x = (unsigned int)f2bf(a0[j]) | ((unsigned int)f2bf(a1[j]) << 16);
                pk.y = (unsigned int)f2bf(a2[j]) | ((unsigned int)f2bf(a3[j]) << 16);
                *(uint2*)&lam_s[e * 520 + (d << 3) + rbase] = pk;
            }
        }
    }
    __syncthreads();

    const int i = i0 + wv;
    const size_t urow = ((size_t)(b * LL + i)) * DD + h * HD_ + lane;
    float u_d = u[urow];
    const float st0 = softplus_f(step_sizes[i]);
    const float st1 = softplus_f(step_sizes[LL + i]);

    const bool up32 = (lane & 32) != 0;
    const bool up16 = (lane & 16) != 0;
    const bool up8  = (lane & 8) != 0;
    const bool up4  = (lane & 4) != 0;
    const bool up2  = (lane & 2) != 0;
    const bool up1  = (lane & 1) != 0;

    // read back own 8 edges: lamr[w][r], lane = d (8x ds_read_b128)
    float lamr[8][8];
#pragma unroll
    for (int w = 0; w < 8; ++w) {
        union U8 { bf16x8s v; unsigned short s[8]; } lv;
        lv.v = *(const bf16x8s*)&lam_s[((wv << 3) + w) * 520 + (lane << 3)];
#pragma unroll
        for (int r = 0; r < 8; ++r) lamr[w][r] = bf2f(lv.s[r]);
    }

    // ss reduce-scatter (xor-32 fused into build); inv_ss lands on lane idx
    float inv_ss;
    {
        float q[32];
#pragma unroll
        for (int wp = 0; wp < 4; ++wp)
#pragma unroll
            for (int r = 0; r < 8; ++r) {
                float plo = lamr[wp][r] * lamr[wp][r];
                float phi = lamr[wp + 4][r] * lamr[wp + 4][r];
                float recv = __shfl_xor(up32 ? plo : phi, 32);
                q[(wp << 3) + r] = (up32 ? phi : plo) + recv;
            }
#pragma unroll
        for (int j = 0; j < 16; ++j) {
            float lo = q[j], hi = q[j + 16];
            float recv = __shfl_xor(up16 ? lo : hi, 16);
            q[j] = (up16 ? hi : lo) + recv;
        }
#pragma unroll
        for (int j = 0; j < 8; ++j) {
            float lo = q[j], hi = q[j + 8];
            float recv = __shfl_xor(up8 ? lo : hi, 8);
            q[j] = (up8 ? hi : lo) + recv;
        }
#pragma unroll
        for (int j = 0; j < 4; ++j) {
            float lo = q[j], hi = q[j + 4];
            float recv = __shfl_xor(up4 ? lo : hi, 4);
            q[j] = (up4 ? hi : lo) + recv;
        }
#pragma unroll
        for (int j = 0; j < 2; ++j) {
            float lo = q[j], hi = q[j + 2];
            float recv = __shfl_xor(up2 ? lo : hi, 2);
            q[j] = (up2 ? hi : lo) + recv;
        }
        {
            float lo = q[0], hi = q[1];
            float recv = __shfl_xor(up1 ? lo : hi, 1);
            q[0] = (up1 ? hi : lo) + recv;
        }
        inv_ss = 1.0f / fmaxf(q[0], 1e-24f);
    }

    // Phase 2: per-edge v rows, rotary cos/sin (table), alpha
    const int k31 = lane & 31;
    float vw[8], cw[8], sw[8], aw[8];
#pragma unroll
    for (int w = 0; w < 8; ++w) {
        const int le = (wv << 3) + w;
        const int j = ejs[le];
        aw[w] = alphs[le];
        vw[w] = v[((size_t)(b * KK + j)) * DD + h * HD_ + lane];
        float2 rc = ((const float2*)rotT)[((size_t)(i - j + 2047) << 5) + k31];
        cw[w] = rc.x;
        sw[w] = rc.y;
    }

#pragma unroll
    for (int t = 0; t < 2; ++t) {
        float upv = __shfl_xor(u_d, 32);
        float rotb = (lane < 32) ? -upv : upv;   // rotate_half
        float resid = 0.0f;
        float q[32];
#pragma unroll
        for (int wp = 0; wp < 4; ++wp) {
            float dlo = fmaf(u_d, cw[wp], rotb * sw[wp]) - vw[wp];
            float dhi = fmaf(u_d, cw[wp + 4], rotb * sw[wp + 4]) - vw[wp + 4];
            resid = fmaf(aw[wp], dlo, resid);
            resid = fmaf(aw[wp + 4], dhi, resid);
#pragma unroll
            for (int r = 0; r < 8; ++r) {
                float plo = lamr[wp][r] * dlo;
                float phi = lamr[wp + 4][r] * dhi;
                float recv = __shfl_xor(up32 ? plo : phi, 32);
                q[(wp << 3) + r] = (up32 ? phi : plo) + recv;
            }
        }
#pragma unroll
        for (int j = 0; j < 16; ++j) {
            float lo = q[j], hi = q[j + 16];
            float recv = __shfl_xor(up16 ? lo : hi, 16);
            q[j] = (up16 ? hi : lo) + recv;
        }
#pragma unroll
        for (int j = 0; j < 8; ++j) {
            float lo = q[j], hi = q[j + 8];
            float recv = __shfl_xor(up8 ? lo : hi, 8);
            q[j] = (up8 ? hi : lo) + recv;
        }
#pragma unroll
        for (int j = 0; j < 4; ++j) {
            float lo = q[j], hi = q[j + 4];
            float recv = __shfl_xor(up4 ? lo : hi, 4);
            q[j] = (up4 ? hi : lo) + recv;
        }
#pragma unroll
        for (int j = 0; j < 2; ++j) {
            float lo = q[j], hi = q[j + 2];
            float recv = __shfl_xor(up2 ? lo : hi, 2);
            q[j] = (up2 ? hi : lo) + recv;
        }
        {
            float lo = q[0], hi = q[1];
            float recv = __shfl_xor(up1 ? lo : hi, 1);
            q[0] = (up1 ? hi : lo) + recv;
        }
        // dt/ss for (w=lane>>3, r=lane&7) sits on lane; share via LDS
        dts[wv][lane] = q[0] * inv_ss;
#pragma unroll
        for (int w = 0; w < 8; ++w) {
            float4 da = *(const float4*)&dts[wv][(w << 3)];
            float4 db = *(const float4*)&dts[wv][(w << 3) + 4];
            resid = fmaf(da.x, lamr[w][0], resid);
            resid = fmaf(da.y, lamr[w][1], resid);
            resid = fmaf(da.z, lamr[w][2], resid);
            resid = fmaf(da.w, lamr[w][3], resid);
            resid = fmaf(db.x, lamr[w][4], resid);
            resid = fmaf(db.y, lamr[w][5], resid);
            resid = fmaf(db.z, lamr[w][6], resid);
            resid = fmaf(db.w, lamr[w][7], resid);
        }
        u_d = fmaf((t == 0) ? -st0 : -st1, resid, u_d);
    }
    u[urow] = u_d;
}

// ---------------------------------------------------------------------------
extern "C" void kernel_launch(void* const* d_in, const int* in_sizes, int n_in,
                              void* d_out, int out_size, void* d_ws, size_t ws_size,
                              hipStream_t stream) {
    (void)in_sizes; (void)n_in; (void)out_size; (void)ws_size;
    const float* target     = (const float*)d_in[0];
    const float* context    = (const float*)d_in[1];
    const float* Wt         = (const float*)d_in[2];
    const float* bt         = (const float*)d_in[3];
    const float* Wc         = (const float*)d_in[4];
    const float* bc         = (const float*)d_in[5];
    const float* Ws1        = (const float*)d_in[6];
    const float* bs1        = (const float*)d_in[7];
    const float* Ws2        = (const float*)d_in[8];
    const float* bs2        = (const float*)d_in[9];
    const float* Wa1        = (const float*)d_in[10];
    const float* ba1        = (const float*)d_in[11];
    const float* Wa2        = (const float*)d_in[12];
    const float* ba2        = (const float*)d_in[13];
    const float* Wl1        = (const float*)d_in[14];
    const float* bl1        = (const float*)d_in[15];
    const float* Wl2        = (const float*)d_in[16];
    const float* bl2        = (const float*)d_in[17];
    const float* step_sizes = (const float*)d_in[18];
    const float* Wo         = (const float*)d_in[19];
    const float* bo         = (const float*)d_in[20];
    float* out = (float*)d_out;

    // Workspace layout (floats). h16bf = 32768 edges * 32 hw = 524288 floats.
    float* ws = (float*)d_ws;
    float* u    = ws;                               // [0, 2097152)
    float* v    = ws + 2097152;                     // [2097152, 4194304)
    float* t64  = ws + 4194304;                     // [4194304, 4456448)
    float* c64  = ws + 4456448;                     // [4456448, 4718592)
    unsigned short* h16bf = (unsigned short*)(ws + 4718592);  // [4718592, 5242880)
    float* alph = ws + 5242880;                     // [5242880, 5275648)
    int*   ej   = (int*)(ws + 5275648);             // [5275648, 5308416)
    float* wct  = ws + 5308416;                     // [5308416, 5341184)
    float* wcc  = ws + 5341184;                     // [5341184, 5373952)
    unsigned short* wl2bfT = (unsigned short*)(ws + 5373952); // [5373952, 5439488)
    // rotT lives in d_out[0 .. 262144): consumed by iterate_k, then the final
    // gemm overwrites the whole out buffer. 262144 <= out_size (2097152).
    float* rotT = out;

    prep_all<<<dim3(656), dim3(256), 0, stream>>>(
        Ws1, Wa1, Wl1, Wl2, bl2, wct, wcc, wl2bfT, rotT);

    gemms_all<<<dim3(640), dim3(256), 0, stream>>>(
        target, context, Wt, bt, Wc, bc, wct, wcc, u, v, t64, c64);

    scores_topk<<<dim3(BB * LL), dim3(256), 0, stream>>>(t64, c64, bs1, Ws2, bs2, ej);

    edge_params<<<dim3(BB * NE / 256), dim3(256), 0, stream>>>(t64, c64, ej, bl1, ba1, Wa2, ba2, h16bf, alph);

    iterate_k<<<dim3(LL / 4, HH, BB), dim3(256), 0, stream>>>(u, v, ej, alph, h16bf, wl2bfT, rotT, step_sizes);

    gemm_bf16<<<dim3(32, 8), dim3(256), 0, stream>>>(u, Wo, bo, out, 4096, 512, 512);
}

// Round 13
// 286.633 us; speedup vs baseline: 1.2114x; 1.0009x over previous
//
#include <hip/hip_runtime.h>
#include <math.h>

// Problem constants
#define BB 2
#define LL 2048
#define KK 2048
#define DD 512
#define HH 8
#define HD_ 64
#define RR 8
#define WWIN 8
#define NE (LL * WWIN)   // 16384 edges per batch

typedef __attribute__((ext_vector_type(8))) short bf16x8s;
typedef __attribute__((ext_vector_type(4))) float f32x4;

__device__ __forceinline__ float gelu_f(float x) {
    return 0.5f * x * (1.0f + erff(x * 0.70710678118654752f));
}
__device__ __forceinline__ float softplus_f(float x) {
    return (x > 20.0f) ? x : log1pf(expf(x));
}
__device__ __forceinline__ unsigned short f2bf(float f) {
    unsigned int x = __float_as_uint(f);
    x += 0x7FFFu + ((x >> 16) & 1u);   // RTNE
    return (unsigned short)(x >> 16);
}
__device__ __forceinline__ float bf2f(unsigned short s) {
    return __uint_as_float(((unsigned int)s) << 16);
}

#define GEMM_SMEM_BYTES 15360   // max(bf16: 10240+5120, f32: 4352+4352)

// ---------------------------------------------------------------------------
// bf16-MFMA GEMM body: C[M,N] = A[M,Kd]@W[Kd,N] (+bias), f32 in/out.
// Tile 128x64, BK=32, 4 waves (2M x 2N), wave tile 64x32, frags 4x2 of 16x16.
// ---------------------------------------------------------------------------
__device__ __forceinline__ void gemm_bf16_body(
    const float* __restrict__ A, const float* __restrict__ W,
    const float* __restrict__ bias, float* __restrict__ C,
    int M, int N, int Kd, int bx, int by, char* smem) {
    short (*As)[40] = (short(*)[40])smem;
    short (*Bs)[40] = (short(*)[40])(smem + 128 * 40 * 2);
    const int tid = threadIdx.x;
    const int m0 = bx * 128, n0 = by * 64;
    const int wv = tid >> 6, lane = tid & 63;
    const int wm = (wv & 1) << 6, wn = (wv >> 1) << 5;
    const int l15 = lane & 15, lg = lane >> 4;

    f32x4 acc[4][2] = {};
    union S8 { bf16x8s v; short s[8]; };

    const int arow = tid >> 1, akh = (tid & 1) << 4;
    const int bk = tid >> 3, bnb = (tid & 7) << 3;

    for (int k0 = 0; k0 < Kd; k0 += 32) {
        {
            const float* ap = &A[(size_t)(m0 + arow) * Kd + k0 + akh];
            float4 f0 = *(const float4*)(ap + 0);
            float4 f1 = *(const float4*)(ap + 4);
            float4 f2 = *(const float4*)(ap + 8);
            float4 f3 = *(const float4*)(ap + 12);
            S8 s0, s1;
            s0.s[0] = f2bf(f0.x); s0.s[1] = f2bf(f0.y); s0.s[2] = f2bf(f0.z); s0.s[3] = f2bf(f0.w);
            s0.s[4] = f2bf(f1.x); s0.s[5] = f2bf(f1.y); s0.s[6] = f2bf(f1.z); s0.s[7] = f2bf(f1.w);
            s1.s[0] = f2bf(f2.x); s1.s[1] = f2bf(f2.y); s1.s[2] = f2bf(f2.z); s1.s[3] = f2bf(f2.w);
            s1.s[4] = f2bf(f3.x); s1.s[5] = f2bf(f3.y); s1.s[6] = f2bf(f3.z); s1.s[7] = f2bf(f3.w);
            *(bf16x8s*)&As[arow][akh] = s0.v;
            *(bf16x8s*)&As[arow][akh + 8] = s1.v;
        }
        {
            const float* wp = &W[(size_t)(k0 + bk) * N + n0 + bnb];
            float4 w0 = *(const float4*)(wp + 0);
            float4 w1 = *(const float4*)(wp + 4);
            Bs[bnb + 0][bk] = f2bf(w0.x);
            Bs[bnb + 1][bk] = f2bf(w0.y);
            Bs[bnb + 2][bk] = f2bf(w0.z);
            Bs[bnb + 3][bk] = f2bf(w0.w);
            Bs[bnb + 4][bk] = f2bf(w1.x);
            Bs[bnb + 5][bk] = f2bf(w1.y);
            Bs[bnb + 6][bk] = f2bf(w1.z);
            Bs[bnb + 7][bk] = f2bf(w1.w);
        }
        __syncthreads();
        bf16x8s af[4], bf[2];
#pragma unroll
        for (int mf = 0; mf < 4; ++mf)
            af[mf] = *(const bf16x8s*)&As[wm + (mf << 4) + l15][lg << 3];
#pragma unroll
        for (int nf = 0; nf < 2; ++nf)
            bf[nf] = *(const bf16x8s*)&Bs[wn + (nf << 4) + l15][lg << 3];
#pragma unroll
        for (int mf = 0; mf < 4; ++mf)
#pragma unroll
            for (int nf = 0; nf < 2; ++nf)
                acc[mf][nf] = __builtin_amdgcn_mfma_f32_16x16x32_bf16(af[mf], bf[nf], acc[mf][nf], 0, 0, 0);
        __syncthreads();
    }
    float bv[2] = {0.f, 0.f};
    if (bias) {
        bv[0] = bias[n0 + wn + l15];
        bv[1] = bias[n0 + wn + 16 + l15];
    }
#pragma unroll
    for (int mf = 0; mf < 4; ++mf)
#pragma unroll
        for (int nf = 0; nf < 2; ++nf)
#pragma unroll
            for (int j = 0; j < 4; ++j) {
                int crow = m0 + wm + (mf << 4) + (lg << 2) + j;
                int ccol = n0 + wn + (nf << 4) + l15;
                C[(size_t)crow * N + ccol] = acc[mf][nf][j] + bv[nf];
            }
}

// ---------------------------------------------------------------------------
// f32 GEMM body (kept for t64/c64: exact scores -> stable top-k).
// ---------------------------------------------------------------------------
__device__ __forceinline__ void gemm_f32_body(
    const float* __restrict__ A, const float* __restrict__ W,
    float* __restrict__ C, int M, int N, int Kd, int bx, int by, char* smem) {
    float (*As)[68] = (float(*)[68])smem;
    float (*Bs)[68] = (float(*)[68])(smem + 16 * 68 * 4);
    const int tid = threadIdx.x;
    const int m0 = bx * 64, n0 = by * 64;
    const int tx = tid & 15, ty = tid >> 4;
    const int row_a = tid >> 2, kq_a = (tid & 3) << 2;
    const int kw = tid >> 4, nq = (tid & 15) << 2;
    float acc[4][4] = {};
    for (int k0 = 0; k0 < Kd; k0 += 16) {
        float4 av = *(const float4*)&A[(size_t)(m0 + row_a) * Kd + k0 + kq_a];
        As[kq_a + 0][row_a] = av.x;
        As[kq_a + 1][row_a] = av.y;
        As[kq_a + 2][row_a] = av.z;
        As[kq_a + 3][row_a] = av.w;
        *(float4*)&Bs[kw][nq] = *(const float4*)&W[(size_t)(k0 + kw) * N + n0 + nq];
        __syncthreads();
#pragma unroll
        for (int k = 0; k < 16; ++k) {
            float4 a4 = *(const float4*)&As[k][ty << 2];
            float4 b4 = *(const float4*)&Bs[k][tx << 2];
            acc[0][0] = fmaf(a4.x, b4.x, acc[0][0]);
            acc[0][1] = fmaf(a4.x, b4.y, acc[0][1]);
            acc[0][2] = fmaf(a4.x, b4.z, acc[0][2]);
            acc[0][3] = fmaf(a4.x, b4.w, acc[0][3]);
            acc[1][0] = fmaf(a4.y, b4.x, acc[1][0]);
            acc[1][1] = fmaf(a4.y, b4.y, acc[1][1]);
            acc[1][2] = fmaf(a4.y, b4.z, acc[1][2]);
            acc[1][3] = fmaf(a4.y, b4.w, acc[1][3]);
            acc[2][0] = fmaf(a4.z, b4.x, acc[2][0]);
            acc[2][1] = fmaf(a4.z, b4.y, acc[2][1]);
            acc[2][2] = fmaf(a4.z, b4.z, acc[2][2]);
            acc[2][3] = fmaf(a4.z, b4.w, acc[2][3]);
            acc[3][0] = fmaf(a4.w, b4.x, acc[3][0]);
            acc[3][1] = fmaf(a4.w, b4.y, acc[3][1]);
            acc[3][2] = fmaf(a4.w, b4.z, acc[3][2]);
            acc[3][3] = fmaf(a4.w, b4.w, acc[3][3]);
        }
        __syncthreads();
    }
#pragma unroll
    for (int q = 0; q < 4; ++q) {
        float4 o;
        o.x = acc[q][0];
        o.y = acc[q][1];
        o.z = acc[q][2];
        o.w = acc[q][3];
        *(float4*)&C[(size_t)(m0 + (ty << 2) + q) * N + n0 + (tx << 2)] = o;
    }
}

// ---------------------------------------------------------------------------
// All 4 projection GEMMs in ONE launch (640 blocks).
// ---------------------------------------------------------------------------
__global__ __launch_bounds__(256) void gemms_all(
    const float* __restrict__ target, const float* __restrict__ context,
    const float* __restrict__ Wt, const float* __restrict__ bt,
    const float* __restrict__ Wc, const float* __restrict__ bc,
    const float* __restrict__ wct, const float* __restrict__ wcc,
    float* __restrict__ u, float* __restrict__ v,
    float* __restrict__ t64, float* __restrict__ c64) {
    __shared__ __align__(16) char smem[GEMM_SMEM_BYTES];
    const int bid = blockIdx.x;
    if (bid < 64) {
        gemm_f32_body(target, wct, t64, 4096, 64, 512, bid, 0, smem);
    } else if (bid < 128) {
        gemm_f32_body(context, wcc, c64, 4096, 64, 512, bid - 64, 0, smem);
    } else if (bid < 384) {
        const int r = bid - 128;
        gemm_bf16_body(target, Wt, bt, u, 4096, 512, 512, r & 31, r >> 5, smem);
    } else {
        const int r = bid - 384;
        gemm_bf16_body(context, Wc, bc, v, 4096, 512, 512, r & 31, r >> 5, smem);
    }
}

__global__ __launch_bounds__(256) void gemm_bf16(
    const float* __restrict__ A, const float* __restrict__ W,
    const float* __restrict__ bias, float* __restrict__ C,
    int M, int N, int Kd) {
    __shared__ __align__(16) char smem[GEMM_SMEM_BYTES];
    gemm_bf16_body(A, W, bias, C, M, N, Kd, blockIdx.x, blockIdx.y, smem);
}

// ---------------------------------------------------------------------------
// prep (656 blocks, one launch, runs FIRST):
//  blocks 0..127   pack Ws1/Wa1/Wl1 -> wct/wcc [512,64]
//  blocks 128..143 build Wl2bfT [4096 col][32 k] bf16, bl2 at k=16
//  blocks 144..655 rotary table rot[delta+2047][k31] -> d_out scratch region
//                  (d_out is only written by the FINAL gemm, after iterate_k
//                  has consumed the table — safe, deterministic, re-written
//                  every call).
// ---------------------------------------------------------------------------
__global__ void prep_all(const float* __restrict__ Ws1, const float* __restrict__ Wa1,
                         const float* __restrict__ Wl1,
                         const float* __restrict__ Wl2, const float* __restrict__ bl2,
                         float* __restrict__ Wct, float* __restrict__ Wcc,
                         unsigned short* __restrict__ wl2bfT,
                         float* __restrict__ rot) {
    if (blockIdx.x < 128) {
        int idx = blockIdx.x * 256 + threadIdx.x;
        int k = idx >> 6, c = idx & 63;
        float vt = 0.f, vc = 0.f;
        if (c < 16)      { vt = Ws1[k * 16 + c];        vc = Ws1[(512 + k) * 16 + c]; }
        else if (c < 32) { vt = Wa1[k * 16 + (c - 16)]; vc = Wa1[(512 + k) * 16 + (c - 16)]; }
        else if (c < 48) { vt = Wl1[k * 16 + (c - 32)]; vc = Wl1[(512 + k) * 16 + (c - 32)]; }
        Wct[idx] = vt;
        Wcc[idx] = vc;
    } else if (blockIdx.x < 144) {
        int c = (blockIdx.x - 128) * 256 + threadIdx.x;   // 0..4095
        union U8 { bf16x8s v; unsigned short s[8]; } r0, r1, r2, r3;
#pragma unroll
        for (int k = 0; k < 8; ++k) r0.s[k] = f2bf(Wl2[(size_t)k * 4096 + c]);
#pragma unroll
        for (int k = 0; k < 8; ++k) r1.s[k] = f2bf(Wl2[(size_t)(k + 8) * 4096 + c]);
#pragma unroll
        for (int k = 0; k < 8; ++k) { r2.s[k] = 0; r3.s[k] = 0; }
        r2.s[0] = f2bf(bl2[c]);   // bias row at k=16 (pairs with h16bf k16 = 1.0)
        unsigned short* dst = &wl2bfT[(size_t)c * 32];
        *(bf16x8s*)(dst + 0)  = r0.v;
        *(bf16x8s*)(dst + 8)  = r1.v;
        *(bf16x8s*)(dst + 16) = r2.v;
        *(bf16x8s*)(dst + 24) = r3.v;
    } else {
        int idx = (blockIdx.x - 144) * 256 + threadIdx.x;   // 0..131071
        int dlt = (idx >> 5) - 2047;
        int k = idx & 31;
        float invf = exp2f((float)k * (-13.287712379549449f / 32.0f));
        float s, c;
        sincosf((float)dlt * invf, &s, &c);
        ((float2*)rot)[idx] = make_float2(c, s);
    }
}

// ---------------------------------------------------------------------------
// Fused scores + top-8 — EXACTLY R8's kernel (1 row/block, 4096 blocks).
// R11's 4-row variant regressed (176us, occupancy 25.6%): the kernel is
// compute/latency bound, not L2-BW bound; high block count is the win.
// ---------------------------------------------------------------------------
__global__ __launch_bounds__(256) void scores_topk(
    const float* __restrict__ t64, const float* __restrict__ c64,
    const float* __restrict__ bs1, const float* __restrict__ Ws2,
    const float* __restrict__ bs2, int* __restrict__ edge_j) {
    __shared__ float sc[KK];
    __shared__ float wvs[4];
    __shared__ int wvj[4];
    const int tid = threadIdx.x;
    const int b = blockIdx.x >> 11;
    const int i = blockIdx.x & (LL - 1);
    float tsb[16], w2[16];
    const float* tr = &t64[(size_t)(b * LL + i) * 64];
#pragma unroll
    for (int k = 0; k < 16; ++k) { tsb[k] = tr[k] + bs1[k]; w2[k] = Ws2[k]; }
    const float b2 = bs2[0];
    for (int j = tid; j < KK; j += 256) {
        const float4* cr4 = (const float4*)&c64[(size_t)(b * KK + j) * 64];
        float creg[16];
        float4 c0 = cr4[0], c1 = cr4[1], c2 = cr4[2], c3 = cr4[3];
        creg[0] = c0.x; creg[1] = c0.y; creg[2] = c0.z; creg[3] = c0.w;
        creg[4] = c1.x; creg[5] = c1.y; creg[6] = c1.z; creg[7] = c1.w;
        creg[8] = c2.x; creg[9] = c2.y; creg[10] = c2.z; creg[11] = c2.w;
        creg[12] = c3.x; creg[13] = c3.y; creg[14] = c3.z; creg[15] = c3.w;
        float s = b2;
#pragma unroll
        for (int k = 0; k < 16; ++k)
            s = fmaf(gelu_f(tsb[k] + creg[k]), w2[k], s);
        sc[j] = s;
    }
    __syncthreads();

    float ls[8];
#pragma unroll
    for (int k = 0; k < 8; ++k) ls[k] = sc[tid + (k << 8)];
    const int lane = tid & 63, wv = tid >> 6;
#pragma unroll
    for (int w = 0; w < WWIN; ++w) {
        float cs = ls[0];
        int ck = 0;
#pragma unroll
        for (int k = 1; k < 8; ++k)
            if (ls[k] > cs) { cs = ls[k]; ck = k; }
        int cj = tid + (ck << 8);
#pragma unroll
        for (int m = 1; m < 64; m <<= 1) {
            float os = __shfl_xor(cs, m);
            int oj = __shfl_xor(cj, m);
            if (os > cs || (os == cs && oj < cj)) { cs = os; cj = oj; }
        }
        if (lane == 0) { wvs[wv] = cs; wvj[wv] = cj; }
        __syncthreads();
        float bsv = wvs[0];
        int bjv = wvj[0];
#pragma unroll
        for (int q = 1; q < 4; ++q) {
            float qs = wvs[q];
            int qj = wvj[q];
            if (qs > bsv || (qs == bsv && qj < bjv)) { bsv = qs; bjv = qj; }
        }
        if (tid == 0) edge_j[(size_t)(b * LL + i) * WWIN + w] = bjv;
        {
            const bool own = (bjv & 255) == tid;
            const int bk = bjv >> 8;
#pragma unroll
            for (int k = 0; k < 8; ++k)
                if (own && bk == k) ls[k] = -INFINITY;
        }
        __syncthreads();
    }
}

// ---------------------------------------------------------------------------
// Per-edge params: h16bf (bf16, MFMA A-layout rows of 32 with k16=1.0) + alpha.
// ---------------------------------------------------------------------------
__global__ __launch_bounds__(256) void edge_params(
    const float* __restrict__ t64, const float* __restrict__ c64,
    const int* __restrict__ edge_j,
    const float* __restrict__ bl1, const float* __restrict__ ba1,
    const float* __restrict__ Wa2, const float* __restrict__ ba2,
    unsigned short* __restrict__ h16bf, float* __restrict__ alpha) {
    int idx = blockIdx.x * 256 + threadIdx.x;
    if (idx >= BB * NE) return;
    int b = idx >> 14;
    int i = (idx & (NE - 1)) >> 3;
    int j = edge_j[idx];
    const float* tr = &t64[(size_t)(b * LL + i) * 64];
    const float* cr = &c64[(size_t)(b * KK + j) * 64];
    union U8 { bf16x8s v; unsigned short s[8]; } o0, o1, o2, o3;
    float s = ba2[0];
#pragma unroll
    for (int k = 0; k < 8; ++k) {
        o0.s[k] = f2bf(gelu_f(tr[32 + k] + cr[32 + k] + bl1[k]));
        s = fmaf(gelu_f(tr[16 + k] + cr[16 + k] + ba1[k]), Wa2[k], s);
    }
#pragma unroll
    for (int k = 8; k < 16; ++k) {
        o1.s[k - 8] = f2bf(gelu_f(tr[32 + k] + cr[32 + k] + bl1[k]));
        s = fmaf(gelu_f(tr[16 + k] + cr[16 + k] + ba1[k]), Wa2[k], s);
    }
#pragma unroll
    for (int k = 0; k < 8; ++k) { o2.s[k] = 0; o3.s[k] = 0; }
    o2.s[0] = 0x3F80;   // bf16(1.0) at k=16: multiplies Wl2bfT's bl2 row
    unsigned short* dst = &h16bf[(size_t)idx * 32];
    *(bf16x8s*)(dst + 0)  = o0.v;
    *(bf16x8s*)(dst + 8)  = o1.v;
    *(bf16x8s*)(dst + 16) = o2.v;
    *(bf16x8s*)(dst + 24) = o3.v;
    alpha[idx] = softplus_f(s);
}

// ---------------------------------------------------------------------------
// Fused T=2 consensus iterations — EXACTLY R8's kernel.
// (256,3): R10's (256,4) forced VGPR 76->64, spilling lamr[8][8] to scratch
// (FETCH 10MB->102MB, dur 124->141). 3 blocks/CU, lamr register-resident.
// ---------------------------------------------------------------------------
__global__ __launch_bounds__(256, 3) void iterate_k(
    float* __restrict__ u, const float* __restrict__ v,
    const int* __restrict__ edge_j, const float* __restrict__ alpha,
    const unsigned short* __restrict__ h16bf,
    const unsigned short* __restrict__ wl2bfT,
    const float* __restrict__ rotT,
    const float* __restrict__ step_sizes) {
    __shared__ unsigned short lam_s[32 * 520];   // [edge][d*8 + r], pad 8/row
    __shared__ float alphs[32];
    __shared__ int ejs[32];
    __shared__ float dts[4][64];
    const int tid = threadIdx.x;
    const int h = blockIdx.y, b = blockIdx.z;
    const int i0 = blockIdx.x << 2;
    const int e0 = b * NE + (i0 << 3);

    if (tid < 32) { ejs[tid] = edge_j[e0 + tid]; alphs[tid] = alpha[e0 + tid]; }

    const int wv = tid >> 6, lane = tid & 63;
    const int l15 = lane & 15, lg = lane >> 4;

    // ---- Phase 1: Lam via MFMA, packed b64 write-out ----
    {
        const int mt = wv & 1;
        const int rbase = (wv >> 1) << 2;
        bf16x8s afrag = *(const bf16x8s*)&h16bf[(size_t)(e0 + (mt << 4) + l15) * 32 + (lg << 3)];
        const unsigned short* wbase = &wl2bfT[((size_t)(h * 512 + (rbase << 6) + l15)) * 32 + (lg << 3)];
#pragma unroll
        for (int g = 0; g < 4; ++g) {
            f32x4 a0 = {0.f, 0.f, 0.f, 0.f}, a1 = a0, a2 = a0, a3 = a0;
            const unsigned short* wg = wbase + g * 512;   // +16 cols
            a0 = __builtin_amdgcn_mfma_f32_16x16x32_bf16(afrag, *(const bf16x8s*)(wg + 0),    a0, 0, 0, 0);
            a1 = __builtin_amdgcn_mfma_f32_16x16x32_bf16(afrag, *(const bf16x8s*)(wg + 2048), a1, 0, 0, 0);
            a2 = __builtin_amdgcn_mfma_f32_16x16x32_bf16(afrag, *(const bf16x8s*)(wg + 4096), a2, 0, 0, 0);
            a3 = __builtin_amdgcn_mfma_f32_16x16x32_bf16(afrag, *(const bf16x8s*)(wg + 6144), a3, 0, 0, 0);
            const int d = (g << 4) + l15;
#pragma unroll
            for (int j = 0; j < 4; ++j) {
                const int e = (mt << 4) + (lg << 2) + j;
                uint2 pk;
                pk.x = (unsigned int)f2bf(a0[j]) | ((unsigned int)f2bf(a1[j]) << 16);
                pk.y = (unsigned int)f2bf(a2[j]) | ((unsigned int)f2bf(a3[j]) << 16);
                *(uint2*)&lam_s[e * 520 + (d << 3) + rbase] = pk;
            }
        }
    }
    __syncthreads();

    const int i = i0 + wv;
    const size_t urow = ((size_t)(b * LL + i)) * DD + h * HD_ + lane;
    float u_d = u[urow];
    const float st0 = softplus_f(step_sizes[i]);
    const float st1 = softplus_f(step_sizes[LL + i]);

    const bool up32 = (lane & 32) != 0;
    const bool up16 = (lane & 16) != 0;
    const bool up8  = (lane & 8) != 0;
    const bool up4  = (lane & 4) != 0;
    const bool up2  = (lane & 2) != 0;
    const bool up1  = (lane & 1) != 0;

    // read back own 8 edges: lamr[w][r], lane = d (8x ds_read_b128)
    float lamr[8][8];
#pragma unroll
    for (int w = 0; w < 8; ++w) {
        union U8 { bf16x8s v; unsigned short s[8]; } lv;
        lv.v = *(const bf16x8s*)&lam_s[((wv << 3) + w) * 520 + (lane << 3)];
#pragma unroll
        for (int r = 0; r < 8; ++r) lamr[w][r] = bf2f(lv.s[r]);
    }

    // ss reduce-scatter (xor-32 fused into build); inv_ss lands on lane idx
    float inv_ss;
    {
        float q[32];
#pragma unroll
        for (int wp = 0; wp < 4; ++wp)
#pragma unroll
            for (int r = 0; r < 8; ++r) {
                float plo = lamr[wp][r] * lamr[wp][r];
                float phi = lamr[wp + 4][r] * lamr[wp + 4][r];
                float recv = __shfl_xor(up32 ? plo : phi, 32);
                q[(wp << 3) + r] = (up32 ? phi : plo) + recv;
            }
#pragma unroll
        for (int j = 0; j < 16; ++j) {
            float lo = q[j], hi = q[j + 16];
            float recv = __shfl_xor(up16 ? lo : hi, 16);
            q[j] = (up16 ? hi : lo) + recv;
        }
#pragma unroll
        for (int j = 0; j < 8; ++j) {
            float lo = q[j], hi = q[j + 8];
            float recv = __shfl_xor(up8 ? lo : hi, 8);
            q[j] = (up8 ? hi : lo) + recv;
        }
#pragma unroll
        for (int j = 0; j < 4; ++j) {
            float lo = q[j], hi = q[j + 4];
            float recv = __shfl_xor(up4 ? lo : hi, 4);
            q[j] = (up4 ? hi : lo) + recv;
        }
#pragma unroll
        for (int j = 0; j < 2; ++j) {
            float lo = q[j], hi = q[j + 2];
            float recv = __shfl_xor(up2 ? lo : hi, 2);
            q[j] = (up2 ? hi : lo) + recv;
        }
        {
            float lo = q[0], hi = q[1];
            float recv = __shfl_xor(up1 ? lo : hi, 1);
            q[0] = (up1 ? hi : lo) + recv;
        }
        inv_ss = 1.0f / fmaxf(q[0], 1e-24f);
    }

    // Phase 2: per-edge v rows, rotary cos/sin (table), alpha
    const int k31 = lane & 31;
    float vw[8], cw[8], sw[8], aw[8];
#pragma unroll
    for (int w = 0; w < 8; ++w) {
        const int le = (wv << 3) + w;
        const int j = ejs[le];
        aw[w] = alphs[le];
        vw[w] = v[((size_t)(b * KK + j)) * DD + h * HD_ + lane];
        float2 rc = ((const float2*)rotT)[((size_t)(i - j + 2047) << 5) + k31];
        cw[w] = rc.x;
        sw[w] = rc.y;
    }

#pragma unroll
    for (int t = 0; t < 2; ++t) {
        float upv = __shfl_xor(u_d, 32);
        float rotb = (lane < 32) ? -upv : upv;   // rotate_half
        float resid = 0.0f;
        float q[32];
#pragma unroll
        for (int wp = 0; wp < 4; ++wp) {
            float dlo = fmaf(u_d, cw[wp], rotb * sw[wp]) - vw[wp];
            float dhi = fmaf(u_d, cw[wp + 4], rotb * sw[wp + 4]) - vw[wp + 4];
            resid = fmaf(aw[wp], dlo, resid);
            resid = fmaf(aw[wp + 4], dhi, resid);
#pragma unroll
            for (int r = 0; r < 8; ++r) {
                float plo = lamr[wp][r] * dlo;
                float phi = lamr[wp + 4][r] * dhi;
                float recv = __shfl_xor(up32 ? plo : phi, 32);
                q[(wp << 3) + r] = (up32 ? phi : plo) + recv;
            }
        }
#pragma unroll
        for (int j = 0; j < 16; ++j) {
            float lo = q[j], hi = q[j + 16];
            float recv = __shfl_xor(up16 ? lo : hi, 16);
            q[j] = (up16 ? hi : lo) + recv;
        }
#pragma unroll
        for (int j = 0; j < 8; ++j) {
            float lo = q[j], hi = q[j + 8];
            float recv = __shfl_xor(up8 ? lo : hi, 8);
            q[j] = (up8 ? hi : lo) + recv;
        }
#pragma unroll
        for (int j = 0; j < 4; ++j) {
            float lo = q[j], hi = q[j + 4];
            float recv = __shfl_xor(up4 ? lo : hi, 4);
            q[j] = (up4 ? hi : lo) + recv;
        }
#pragma unroll
        for (int j = 0; j < 2; ++j) {
            float lo = q[j], hi = q[j + 2];
            float recv = __shfl_xor(up2 ? lo : hi, 2);
            q[j] = (up2 ? hi : lo) + recv;
        }
        {
            float lo = q[0], hi = q[1];
            float recv = __shfl_xor(up1 ? lo : hi, 1);
            q[0] = (up1 ? hi : lo) + recv;
        }
        // dt/ss for (w=lane>>3, r=lane&7) sits on lane; share via LDS
        dts[wv][lane] = q[0] * inv_ss;
#pragma unroll
        for (int w = 0; w < 8; ++w) {
            float4 da = *(const float4*)&dts[wv][(w << 3)];
            float4 db = *(const float4*)&dts[wv][(w << 3) + 4];
            resid = fmaf(da.x, lamr[w][0], resid);
            resid = fmaf(da.y, lamr[w][1], resid);
            resid = fmaf(da.z, lamr[w][2], resid);
            resid = fmaf(da.w, lamr[w][3], resid);
            resid = fmaf(db.x, lamr[w][4], resid);
            resid = fmaf(db.y, lamr[w][5], resid);
            resid = fmaf(db.z, lamr[w][6], resid);
            resid = fmaf(db.w, lamr[w][7], resid);
        }
        u_d = fmaf((t == 0) ? -st0 : -st1, resid, u_d);
    }
    u[urow] = u_d;
}

// ---------------------------------------------------------------------------
extern "C" void kernel_launch(void* const* d_in, const int* in_sizes, int n_in,
                              void* d_out, int out_size, void* d_ws, size_t ws_size,
                              hipStream_t stream) {
    (void)in_sizes; (void)n_in; (void)out_size; (void)ws_size;
    const float* target     = (const float*)d_in[0];
    const float* context    = (const float*)d_in[1];
    const float* Wt         = (const float*)d_in[2];
    const float* bt         = (const float*)d_in[3];
    const float* Wc         = (const float*)d_in[4];
    const float* bc         = (const float*)d_in[5];
    const float* Ws1        = (const float*)d_in[6];
    const float* bs1        = (const float*)d_in[7];
    const float* Ws2        = (const float*)d_in[8];
    const float* bs2        = (const float*)d_in[9];
    const float* Wa1        = (const float*)d_in[10];
    const float* ba1        = (const float*)d_in[11];
    const float* Wa2        = (const float*)d_in[12];
    const float* ba2        = (const float*)d_in[13];
    const float* Wl1        = (const float*)d_in[14];
    const float* bl1        = (const float*)d_in[15];
    const float* Wl2        = (const float*)d_in[16];
    const float* bl2        = (const float*)d_in[17];
    const float* step_sizes = (const float*)d_in[18];
    const float* Wo         = (const float*)d_in[19];
    const float* bo         = (const float*)d_in[20];
    float* out = (float*)d_out;

    // Workspace layout (floats). h16bf = 32768 edges * 32 hw = 524288 floats.
    float* ws = (float*)d_ws;
    float* u    = ws;                               // [0, 2097152)
    float* v    = ws + 2097152;                     // [2097152, 4194304)
    float* t64  = ws + 4194304;                     // [4194304, 4456448)
    float* c64  = ws + 4456448;                     // [4456448, 4718592)
    unsigned short* h16bf = (unsigned short*)(ws + 4718592);  // [4718592, 5242880)
    float* alph = ws + 5242880;                     // [5242880, 5275648)
    int*   ej   = (int*)(ws + 5275648);             // [5275648, 5308416)
    float* wct  = ws + 5308416;                     // [5308416, 5341184)
    float* wcc  = ws + 5341184;                     // [5341184, 5373952)
    unsigned short* wl2bfT = (unsigned short*)(ws + 5373952); // [5373952, 5439488)
    // rotT lives in d_out[0 .. 262144): consumed by iterate_k, then the final
    // gemm overwrites the whole out buffer. 262144 <= out_size (2097152).
    float* rotT = out;

    prep_all<<<dim3(656), dim3(256), 0, stream>>>(
        Ws1, Wa1, Wl1, Wl2, bl2, wct, wcc, wl2bfT, rotT);

    gemms_all<<<dim3(640), dim3(256), 0, stream>>>(
        target, context, Wt, bt, Wc, bc, wct, wcc, u, v, t64, c64);

    scores_topk<<<dim3(BB * LL), dim3(256), 0, stream>>>(t64, c64, bs1, Ws2, bs2, ej);

    edge_params<<<dim3(BB * NE / 256), dim3(256), 0, stream>>>(t64, c64, ej, bl1, ba1, Wa2, ba2, h16bf, alph);

    iterate_k<<<dim3(LL / 4, HH, BB), dim3(256), 0, stream>>>(u, v, ej, alph, h16bf, wl2bfT, rotT, step_sizes);

    gemm_bf16<<<dim3(32, 8), dim3(256), 0, stream>>>(u, Wo, bo, out, 4096, 512, 512);
}